// Round 20
// baseline (762.437 us; speedup 1.0000x reference)
//
#include <hip/hip_runtime.h>
#include <hip/hip_bf16.h>
#include <hip/hip_cooperative_groups.h>

namespace cg = cooperative_groups;

#define NN 50000
#define NE 600000
#define DD 128
#define NR 8
#define NB (NN * NR)                   // 400000 (dst,rel) bins
#define NCHUNK8 ((NB + 255) / 256)     // 1563 scan chunks
#define PERT ((NCHUNK8 + 255) / 256)   // 7 items/thread in bscan
#define CAPE 1024                      // LDS edge-slice capacity per block
#define COOPB 1024                     // cooperative grid blocks (4/CU, safely co-resident)

typedef __attribute__((ext_vector_type(8))) short bf16x8;
typedef __attribute__((ext_vector_type(4))) float f32x4;

__device__ __forceinline__ unsigned short f2bf(float f) {
  __hip_bfloat16 h = __float2bfloat16(f);
  return *reinterpret_cast<unsigned short*>(&h);
}
__device__ __forceinline__ unsigned pk2(float lo, float hi) {
  return (unsigned)f2bf(lo) | ((unsigned)f2bf(hi) << 16);
}
__device__ __forceinline__ float bflo(unsigned u) { return __uint_as_float(u << 16); }
__device__ __forceinline__ float bfhi(unsigned u) { return __uint_as_float(u & 0xffff0000u); }

// =============== single cooperative prep kernel ===============
// Phase A: convw (LDS tile transpose) + convh + zero deg
// sync -> B: hist  -> sync -> C: bsum  -> sync -> D: bscan(block0)
// sync -> E: expand -> sync -> F: fill
__global__ __launch_bounds__(256) void csr_coop_kernel(
    const float* __restrict__ W1, const float* __restrict__ Ws1,
    const float* __restrict__ W2, const float* __restrict__ Ws2,
    const float* __restrict__ emb, const int* __restrict__ ids,
    const int* __restrict__ srcA, const int* __restrict__ dstA,
    const int* __restrict__ etA,
    unsigned short* __restrict__ WT, unsigned short* __restrict__ h0,
    int* deg, int* off8, int* __restrict__ eidx,
    int* __restrict__ bsum, int* __restrict__ bbase)
{
  cg::grid_group grid = cg::this_grid();
  __shared__ float tile[16][17];
  __shared__ int tmp[256];

  const int t = threadIdx.x;
  const int b = blockIdx.x;
  const int nthr = COOPB * 256;
  const int gid0 = b * 256 + t;
  const int tx = t & 15, ty = t >> 4;

  // ---- Phase A1: convw — one 16x16 tile per block-iteration ----
  for (int tileId = b; tileId < 18 * 64; tileId += COOPB) {
    const int m = tileId >> 6, t8 = tileId & 63;
    const int d0 = (t8 >> 3) * 16, o0 = (t8 & 7) * 16;
    const float* sw;
    if (m < 8)       sw = W1 + (size_t)m * DD * DD;
    else if (m == 8) sw = Ws1;
    else if (m < 17) sw = W2 + (size_t)(m - 9) * DD * DD;
    else             sw = Ws2;
    __syncthreads();                                        // guard tile reuse
    tile[ty][tx] = sw[(size_t)(d0 + ty) * DD + o0 + tx];    // coalesced in tx
    __syncthreads();
    WT[(size_t)m * DD * DD + (o0 + ty) * DD + d0 + tx] = f2bf(tile[tx][ty]);
  }

  // ---- Phase A2: convh ----
  for (int gid = gid0; gid < NN * 16; gid += nthr) {
    const int row = gid >> 4;
    const int off = (gid & 15) * 8;
    const int srcRow = ids[row];
    const float* s = emb + (size_t)srcRow * DD + off;
    const float4 a = *reinterpret_cast<const float4*>(s);
    const float4 c = *reinterpret_cast<const float4*>(s + 4);
    uint4 u;
    u.x = pk2(a.x, a.y); u.y = pk2(a.z, a.w);
    u.z = pk2(c.x, c.y); u.w = pk2(c.z, c.w);
    *reinterpret_cast<uint4*>(h0 + (size_t)row * DD + off) = u;
  }

  // ---- Phase A3: zero deg ----
  for (int i = gid0; i < NB; i += nthr) deg[i] = 0;

  grid.sync();

  // ---- Phase B: hist ----
  for (int e = gid0; e < NE; e += nthr)
    atomicAdd(&deg[dstA[e] * NR + etA[e]], 1);

  grid.sync();

  // ---- Phase C: bsum per 256-chunk ----
  for (int ch = b; ch < NCHUNK8; ch += COOPB) {
    const int i = ch * 256 + t;
    __syncthreads();                                        // guard tmp reuse
    tmp[t] = (i < NB) ? deg[i] : 0;
    __syncthreads();
#pragma unroll
    for (int off = 128; off > 0; off >>= 1) {
      if (t < off) tmp[t] += tmp[t + off];
      __syncthreads();
    }
    if (t == 0) bsum[ch] = tmp[0];
  }

  grid.sync();

  // ---- Phase D: bscan (block 0 only) ----
  if (b == 0) {
    const int bb = t * PERT;
    const int ee = min(bb + PERT, NCHUNK8);
    int s = 0;
    for (int i = bb; i < ee; ++i) s += bsum[i];
    __syncthreads();                                        // guard tmp reuse
    tmp[t] = s;
    __syncthreads();
#pragma unroll
    for (int off = 1; off < 256; off <<= 1) {
      const int x = (t >= off) ? tmp[t - off] : 0;
      __syncthreads();
      tmp[t] += x;
      __syncthreads();
    }
    int run = tmp[t] - s;                                   // exclusive base
    for (int i = bb; i < ee; ++i) {
      const int v = bsum[i];
      bbase[i] = run;
      run += v;
    }
  }

  grid.sync();

  // ---- Phase E: expand per 256-chunk ----
  for (int ch = b; ch < NCHUNK8; ch += COOPB) {
    const int i = ch * 256 + t;
    const int v = (i < NB) ? deg[i] : 0;
    __syncthreads();                                        // guard tmp reuse
    tmp[t] = v;
    __syncthreads();
#pragma unroll
    for (int off = 1; off < 256; off <<= 1) {
      const int x = (t >= off) ? tmp[t - off] : 0;
      __syncthreads();
      tmp[t] += x;
      __syncthreads();
    }
    const int base = bbase[ch];
    const int excl = base + tmp[t] - v;
    if (i < NB) {
      off8[i] = excl;
      deg[i] = excl;                 // fill cursor
      if (i == NB - 1) off8[NB] = base + tmp[t];
    }
  }

  grid.sync();

  // ---- Phase F: fill ----
  for (int e = gid0; e < NE; e += nthr) {
    const int pos = atomicAdd(&deg[dstA[e] * NR + etA[e]], 1);
    eidx[pos] = srcA[e];
  }
}

// ---------------- gather: sum h[src] rows of one bin into a B-fragment ----------------
__device__ __forceinline__ void gather_frag_lds(
    const unsigned short* __restrict__ h,
    const int* __restrict__ eidx, const int* ldsE, int blockBeg,
    int beg, int end, int g, bf16x8* frag)
{
  float s[4][8];
#pragma unroll
  for (int ks = 0; ks < 4; ++ks)
#pragma unroll
    for (int j = 0; j < 8; ++j) s[ks][j] = 0.f;
  for (int i = beg; i < end; ++i) {
    const int li = i - blockBeg;
    const int idx = (li < CAPE) ? ldsE[li] : eidx[i];
    const unsigned short* hp = h + (size_t)idx * DD + g * 8;
#pragma unroll
    for (int ks = 0; ks < 4; ++ks) {
      const uint4 q = *reinterpret_cast<const uint4*>(hp + ks * 32);
      s[ks][0] += bflo(q.x); s[ks][1] += bfhi(q.x);
      s[ks][2] += bflo(q.y); s[ks][3] += bfhi(q.y);
      s[ks][4] += bflo(q.z); s[ks][5] += bfhi(q.z);
      s[ks][6] += bflo(q.w); s[ks][7] += bfhi(q.w);
    }
  }
#pragma unroll
  for (int ks = 0; ks < 4; ++ks) {
    uint4 u;
    u.x = pk2(s[ks][0], s[ks][1]);
    u.y = pk2(s[ks][2], s[ks][3]);
    u.z = pk2(s[ks][4], s[ks][5]);
    u.w = pk2(s[ks][6], s[ks][7]);
    frag[ks] = *reinterpret_cast<bf16x8*>(&u);
  }
}

// ---------------- fused RGCN layer: 64 nodes/block, K-half W staging (R13/R18-exact) ----------------
template<int OUTF32>
__global__ __launch_bounds__(256, 4) void layer_kernel(
    const unsigned short* __restrict__ h,      // [NN][128] bf16 (read-only)
    const int* __restrict__ off8, const int* __restrict__ eidx,
    const unsigned short* __restrict__ WTl,    // this layer: [9][128][128] bf16 [o][d]
    const float* __restrict__ bias,
    void* __restrict__ out)                    // [NN][128] bf16 or f32
{
  __shared__ __align__(16) char ldsW[2][DD * 64 * 2];   // 2 x 16 KB, XOR-swizzled
  __shared__ int ldsO[64 * NR + 1];                     // block's offset slice (2 KB)
  __shared__ int ldsE[CAPE];                            // block's edge slice  (4 KB)

  const int tid = threadIdx.x;
  const int rowBase = blockIdx.x * 64;
  const int lane = tid & 63;
  const int w = tid >> 6;            // 0..3
  const int c = lane & 15;           // node selector
  const int g = lane >> 4;           // k group
  const int n = rowBase + w * 16 + c;
  const int nld = (n < NN) ? n : (NN - 1);
  const int lnode = nld - rowBase;

  // ---- stage CSR slice ----
  const int nNodes = (NN - rowBase < 64) ? (NN - rowBase) : 64;
  const int onum = nNodes * NR + 1;
  for (int i = tid; i < onum; i += 256) ldsO[i] = off8[rowBase * NR + i];
  __syncthreads();
  const int blockBeg = ldsO[0];
  const int blockCnt = ldsO[onum - 1] - blockBeg;
  const int stCnt = (blockCnt < CAPE) ? blockCnt : CAPE;
  for (int i = tid; i < stCnt; i += 256) ldsE[i] = eidx[blockBeg + i];

  // W staging geometry: 1024 chunks of 16B per half; thread owns 4.
  int dstB[4], srcRel[4];
#pragma unroll
  for (int j = 0; j < 4; ++j) {
    const int i = tid + j * 256;     // 0..1023
    const int o = i >> 3, slot = i & 7;
    dstB[j] = ((o << 7) | (slot << 4)) ^ ((o & 7) << 4);
    srcRel[j] = o * DD + slot * 8;
  }

  uint4 wreg[4];
#pragma unroll
  for (int j = 0; j < 4; ++j)
    wreg[j] = *reinterpret_cast<const uint4*>(WTl + srcRel[j]);
#pragma unroll
  for (int j = 0; j < 4; ++j)
    *reinterpret_cast<uint4*>(ldsW[0] + dstB[j]) = wreg[j];
  __syncthreads();                   // ldsE + ldsW[0] ready

  bf16x8 fA[4], fB[4];
  gather_frag_lds(h, eidx, ldsE, blockBeg, ldsO[lnode * NR], ldsO[lnode * NR + 1], g, fA);

  f32x4 acc[8];
#pragma unroll
  for (int t = 0; t < 8; ++t) acc[t] = (f32x4){0.f, 0.f, 0.f, 0.f};

#define PH(P, CUR, NXT)                                                               \
  {                                                                                   \
    __syncthreads();                                                                  \
    if ((P) < 17) {                                                                   \
      const unsigned short* wsrc = WTl                                                \
          + (size_t)(((P) + 1) >> 1) * DD * DD + (((P) + 1) & 1) * 64;                \
      _Pragma("unroll")                                                               \
      for (int j = 0; j < 4; ++j)                                                     \
        wreg[j] = *reinterpret_cast<const uint4*>(wsrc + srcRel[j]);                  \
    }                                                                                 \
    int gb = 0, ge = 0;                                                               \
    if (((P) & 1) == 0 && ((P) >> 1) + 1 < NR) {                                      \
      const int lo = lnode * NR + ((P) >> 1) + 1;                                     \
      gb = ldsO[lo]; ge = ldsO[lo + 1];                                               \
    }                                                                                 \
    _Pragma("unroll")                                                                 \
    for (int kl = 0; kl < 2; ++kl) {                                                  \
      _Pragma("unroll")                                                               \
      for (int t = 0; t < 8; ++t) {                                                   \
        const int addr = (((t * 16 + c) << 7) + ((kl * 4 + g) << 4)) ^ ((c & 7) << 4); \
        bf16x8 a = *reinterpret_cast<const bf16x8*>(ldsW[(P) & 1] + addr);            \
        acc[t] = __builtin_amdgcn_mfma_f32_16x16x32_bf16(                             \
            a, CUR[((P) & 1) * 2 + kl], acc[t], 0, 0, 0);                             \
      }                                                                               \
    }                                                                                 \
    if (((P) & 1) == 0) {                                                             \
      if (((P) >> 1) + 1 < NR) {                                                      \
        gather_frag_lds(h, eidx, ldsE, blockBeg, gb, ge, g, NXT);                     \
      } else if (((P) >> 1) + 1 == NR) {                                              \
        _Pragma("unroll")                                                             \
        for (int ks = 0; ks < 4; ++ks)                                                \
          NXT[ks] = *reinterpret_cast<const bf16x8*>(                                 \
              h + (size_t)nld * DD + ks * 32 + g * 8);                                \
      }                                                                               \
    }                                                                                 \
    if ((P) < 17) {                                                                   \
      _Pragma("unroll")                                                               \
      for (int j = 0; j < 4; ++j)                                                     \
        *reinterpret_cast<uint4*>(ldsW[((P) + 1) & 1] + dstB[j]) = wreg[j];           \
    }                                                                                 \
  }

  PH(0, fA, fB)  PH(1, fA, fB)
  PH(2, fB, fA)  PH(3, fB, fA)
  PH(4, fA, fB)  PH(5, fA, fB)
  PH(6, fB, fA)  PH(7, fB, fA)
  PH(8, fA, fB)  PH(9, fA, fB)
  PH(10, fB, fA) PH(11, fB, fA)
  PH(12, fA, fB) PH(13, fA, fB)
  PH(14, fB, fA) PH(15, fB, fA)
  PH(16, fA, fB) PH(17, fA, fB)
#undef PH

  if (n >= NN) return;
  if (OUTF32) {
    float* dst = (float*)out + (size_t)n * DD;
#pragma unroll
    for (int t = 0; t < 8; ++t) {
      const int o0 = t * 16 + g * 4;
      const float4 bv = *reinterpret_cast<const float4*>(bias + o0);
      float4 o;
      o.x = acc[t][0] + bv.x; o.y = acc[t][1] + bv.y;
      o.z = acc[t][2] + bv.z; o.w = acc[t][3] + bv.w;
      *reinterpret_cast<float4*>(dst + o0) = o;
    }
  } else {
    unsigned short* dst = (unsigned short*)out + (size_t)n * DD;
#pragma unroll
    for (int t = 0; t < 8; ++t) {
      const int o0 = t * 16 + g * 4;
      const float4 bv = *reinterpret_cast<const float4*>(bias + o0);
      uint2 q;
      q.x = pk2(acc[t][0] + bv.x, acc[t][1] + bv.y);
      q.y = pk2(acc[t][2] + bv.z, acc[t][3] + bv.w);
      *reinterpret_cast<uint2*>(dst + o0) = q;
    }
  }
}

extern "C" void kernel_launch(void* const* d_in, const int* in_sizes, int n_in,
                              void* d_out, int out_size, void* d_ws, size_t ws_size,
                              hipStream_t stream) {
  const int*   node_ids = (const int*)d_in[0];
  const int*   src   = (const int*)d_in[1];
  const int*   dst   = (const int*)d_in[2];
  const int*   etype = (const int*)d_in[3];
  const float* emb   = (const float*)d_in[4];
  const float* W1    = (const float*)d_in[5];
  const float* Ws1   = (const float*)d_in[6];
  const float* b1    = (const float*)d_in[7];
  const float* W2    = (const float*)d_in[8];
  const float* Ws2   = (const float*)d_in[9];
  const float* b2    = (const float*)d_in[10];

  // ws layout (~35 MB):
  //   h0     bf16 [NN*DD]       12.8 MB
  //   h1     bf16 [NN*DD]       12.8 MB
  //   WT     bf16 [18*DD*DD]     0.59 MB
  //   off8   i32  [NB+1]         1.6 MB
  //   deg8   i32  [NB]           1.6 MB
  //   eidx   i32  [NE]           2.4 MB
  //   bsum/bbase i32 [NCHUNK8]
  char* p = (char*)d_ws;
  unsigned short* h0 = (unsigned short*)p;  p += (size_t)NN * DD * 2;
  unsigned short* h1 = (unsigned short*)p;  p += (size_t)NN * DD * 2;
  unsigned short* WT = (unsigned short*)p;  p += (size_t)18 * DD * DD * 2;
  int* off8          = (int*)p;             p += (size_t)(NB + 1) * 4;
  int* deg8          = (int*)p;             p += (size_t)NB * 4;
  int* eidx          = (int*)p;             p += (size_t)NE * 4;
  int* bsum          = (int*)p;             p += (size_t)NCHUNK8 * 4;
  int* bbase         = (int*)p;

  const int tb = (NN + 63) / 64;     // 782

  // single cooperative prep kernel (convw + convh + CSR build)
  {
    void* args[] = {
      (void*)&W1, (void*)&Ws1, (void*)&W2, (void*)&Ws2,
      (void*)&emb, (void*)&node_ids,
      (void*)&src, (void*)&dst, (void*)&etype,
      (void*)&WT, (void*)&h0,
      (void*)&deg8, (void*)&off8, (void*)&eidx,
      (void*)&bsum, (void*)&bbase
    };
    hipLaunchCooperativeKernel((void*)csr_coop_kernel,
                               dim3(COOPB), dim3(256), args, 0, stream);
  }

  layer_kernel<0><<<tb, 256, 0, stream>>>(h0, off8, eidx, WT, b1, h1);
  layer_kernel<1><<<tb, 256, 0, stream>>>(h1, off8, eidx, WT + (size_t)9 * DD * DD, b2, (float*)d_out);
}

// Round 21
// 322.056 us; speedup vs baseline: 2.3674x; 2.3674x over previous
//
#include <hip/hip_runtime.h>
#include <hip/hip_bf16.h>

#define NN 50000
#define NE 600000
#define DD 128
#define NR 8
#define NB (NN * NR)                   // 400000 (dst,rel) bins
#define NCHUNK8 ((NB + 255) / 256)     // 1563 scan blocks
#define PERT ((NCHUNK8 + 255) / 256)   // 7 items/thread in bscan
#define CAPE 1024                      // LDS edge-slice capacity per block

typedef __attribute__((ext_vector_type(8))) short bf16x8;
typedef __attribute__((ext_vector_type(4))) float f32x4;

__device__ __forceinline__ unsigned short f2bf(float f) {
  __hip_bfloat16 h = __float2bfloat16(f);
  return *reinterpret_cast<unsigned short*>(&h);
}
__device__ __forceinline__ unsigned pk2(float lo, float hi) {
  return (unsigned)f2bf(lo) | ((unsigned)f2bf(hi) << 16);
}
__device__ __forceinline__ float bflo(unsigned u) { return __uint_as_float(u << 16); }
__device__ __forceinline__ float bfhi(unsigned u) { return __uint_as_float(u & 0xffff0000u); }

// ---------------- weight transpose+convert (coalesced LDS tile version) ----------------
__global__ __launch_bounds__(256) void convw_kernel(
    const float* __restrict__ W1, const float* __restrict__ Ws1,
    const float* __restrict__ W2, const float* __restrict__ Ws2,
    unsigned short* __restrict__ WT)
{
  __shared__ float tile[16][17];
  const int m = blockIdx.y;
  const int t8 = blockIdx.x;
  const int d0 = (t8 >> 3) * 16, o0 = (t8 & 7) * 16;
  const float* src;
  if (m < 8)       src = W1 + (size_t)m * DD * DD;
  else if (m == 8) src = Ws1;
  else if (m < 17) src = W2 + (size_t)(m - 9) * DD * DD;
  else             src = Ws2;
  const int tx = threadIdx.x & 15, ty = threadIdx.x >> 4;
  tile[ty][tx] = src[(size_t)(d0 + ty) * DD + o0 + tx];
  __syncthreads();
  WT[(size_t)m * DD * DD + (o0 + ty) * DD + d0 + tx] = f2bf(tile[tx][ty]);
}

// ---------------- h0 = bf16(emb[node_ids]) ----------------
__global__ __launch_bounds__(256) void convh_kernel(
    const float* __restrict__ emb, const int* __restrict__ ids,
    unsigned short* __restrict__ h)
{
  const int gid = blockIdx.x * 256 + threadIdx.x;
  if (gid >= NN * 16) return;
  const int row = gid >> 4;
  const int off = (gid & 15) * 8;
  const int srcRow = ids[row];
  const float* src = emb + (size_t)srcRow * DD + off;
  const float4 a = *reinterpret_cast<const float4*>(src);
  const float4 b = *reinterpret_cast<const float4*>(src + 4);
  uint4 u;
  u.x = pk2(a.x, a.y); u.y = pk2(a.z, a.w);
  u.z = pk2(b.x, b.y); u.w = pk2(b.z, b.w);
  *reinterpret_cast<uint4*>(h + (size_t)row * DD + off) = u;
}

// ---------------- CSR build over (dst,rel) bins ----------------
__global__ __launch_bounds__(256) void hist_kernel(
    const int* __restrict__ dst, const int* __restrict__ et,
    int* __restrict__ deg)
{
  const int e = blockIdx.x * 256 + threadIdx.x;
  if (e < NE) atomicAdd(&deg[dst[e] * NR + et[e]], 1);
}

__global__ __launch_bounds__(256) void bsum_kernel(
    const int* __restrict__ deg, int* __restrict__ bsum)
{
  __shared__ int tmp[256];
  const int t = threadIdx.x;
  const int i = blockIdx.x * 256 + t;
  tmp[t] = (i < NB) ? deg[i] : 0;
  __syncthreads();
#pragma unroll
  for (int off = 128; off > 0; off >>= 1) {
    if (t < off) tmp[t] += tmp[t + off];
    __syncthreads();
  }
  if (t == 0) bsum[blockIdx.x] = tmp[0];
}

__global__ __launch_bounds__(256) void bscan_kernel(
    const int* __restrict__ bsum, int* __restrict__ bbase)
{
  __shared__ int tmp[256];
  const int t = threadIdx.x;
  const int b = t * PERT;
  const int e = min(b + PERT, NCHUNK8);
  int s = 0;
  for (int i = b; i < e; ++i) s += bsum[i];
  tmp[t] = s;
  __syncthreads();
#pragma unroll
  for (int off = 1; off < 256; off <<= 1) {
    const int x = (t >= off) ? tmp[t - off] : 0;
    __syncthreads();
    tmp[t] += x;
    __syncthreads();
  }
  int run = tmp[t] - s;
  for (int i = b; i < e; ++i) {
    const int v = bsum[i];
    bbase[i] = run;
    run += v;
  }
}

__global__ __launch_bounds__(256) void expand_kernel(
    int* deg, const int* __restrict__ bbase, int* __restrict__ offsets)
{
  __shared__ int tmp[256];
  const int t = threadIdx.x;
  const int i = blockIdx.x * 256 + t;
  const int v = (i < NB) ? deg[i] : 0;
  tmp[t] = v;
  __syncthreads();
#pragma unroll
  for (int off = 1; off < 256; off <<= 1) {
    const int x = (t >= off) ? tmp[t - off] : 0;
    __syncthreads();
    tmp[t] += x;
    __syncthreads();
  }
  const int base = bbase[blockIdx.x];
  const int excl = base + tmp[t] - v;
  if (i < NB) {
    offsets[i] = excl;
    deg[i] = excl;                  // fill cursor
    if (i == NB - 1) offsets[NB] = base + tmp[t];
  }
}

__global__ __launch_bounds__(256) void fill_kernel(
    const int* __restrict__ src, const int* __restrict__ dst,
    const int* __restrict__ et, int* __restrict__ cursor,
    int* __restrict__ eidx)
{
  const int e = blockIdx.x * 256 + threadIdx.x;
  if (e < NE) {
    const int pos = atomicAdd(&cursor[dst[e] * NR + et[e]], 1);
    eidx[pos] = src[e];
  }
}

// ---------------- gather: sum h[src] rows of one bin into a B-fragment ----------------
__device__ __forceinline__ void gather_frag_lds(
    const unsigned short* __restrict__ h,
    const int* __restrict__ eidx, const int* ldsE, int blockBeg,
    int beg, int end, int g, bf16x8* frag)
{
  float s[4][8];
#pragma unroll
  for (int ks = 0; ks < 4; ++ks)
#pragma unroll
    for (int j = 0; j < 8; ++j) s[ks][j] = 0.f;
  for (int i = beg; i < end; ++i) {
    const int li = i - blockBeg;
    const int idx = (li < CAPE) ? ldsE[li] : eidx[i];
    const unsigned short* hp = h + (size_t)idx * DD + g * 8;
#pragma unroll
    for (int ks = 0; ks < 4; ++ks) {
      const uint4 q = *reinterpret_cast<const uint4*>(hp + ks * 32);
      s[ks][0] += bflo(q.x); s[ks][1] += bfhi(q.x);
      s[ks][2] += bflo(q.y); s[ks][3] += bfhi(q.y);
      s[ks][4] += bflo(q.z); s[ks][5] += bfhi(q.z);
      s[ks][6] += bflo(q.w); s[ks][7] += bfhi(q.w);
    }
  }
#pragma unroll
  for (int ks = 0; ks < 4; ++ks) {
    uint4 u;
    u.x = pk2(s[ks][0], s[ks][1]);
    u.y = pk2(s[ks][2], s[ks][3]);
    u.z = pk2(s[ks][4], s[ks][5]);
    u.w = pk2(s[ks][6], s[ks][7]);
    frag[ks] = *reinterpret_cast<bf16x8*>(&u);
  }
}

// ---------------- relation-split fused layer ----------------
// grid (782, 2). grp=blockIdx.y: 0 -> rels {0,1,2,3}+self (10 phases), writes pA (f32)
//                                1 -> rels {4,5,6,7}      (8 phases), writes pB (f32)
// Block body is R13-shaped: same registers, same LDS, K-half W double-buffer.
__global__ __launch_bounds__(256, 4) void layer_split_kernel(
    const unsigned short* __restrict__ h,      // [NN][128] bf16
    const int* __restrict__ off8, const int* __restrict__ eidx,
    const unsigned short* __restrict__ WTl,    // this layer: [9][128][128] bf16 [o][d]
    float* __restrict__ pA, float* __restrict__ pB)
{
  __shared__ __align__(16) char ldsW[2][DD * 64 * 2];   // 2 x 16 KB, XOR-swizzled
  __shared__ int ldsO[64 * NR + 1];
  __shared__ int ldsE[CAPE];

  const int tid = threadIdx.x;
  const int grp = blockIdx.y;        // uniform per block
  const int rowBase = blockIdx.x * 64;
  const int lane = tid & 63;
  const int w = tid >> 6;
  const int c = lane & 15;
  const int g = lane >> 4;
  const int n = rowBase + w * 16 + c;
  const int nld = (n < NN) ? n : (NN - 1);
  const int lnode = nld - rowBase;
  const int nph = grp ? 8 : 10;

  // ---- stage CSR slice ----
  const int nNodes = (NN - rowBase < 64) ? (NN - rowBase) : 64;
  const int onum = nNodes * NR + 1;
  for (int i = tid; i < onum; i += 256) ldsO[i] = off8[rowBase * NR + i];
  __syncthreads();
  const int blockBeg = ldsO[0];
  const int blockCnt = ldsO[onum - 1] - blockBeg;
  const int stCnt = (blockCnt < CAPE) ? blockCnt : CAPE;
  for (int i = tid; i < stCnt; i += 256) ldsE[i] = eidx[blockBeg + i];

  // W staging geometry (same as R13)
  int dstB[4], srcRel[4];
#pragma unroll
  for (int j = 0; j < 4; ++j) {
    const int i = tid + j * 256;
    const int o = i >> 3, slot = i & 7;
    dstB[j] = ((o << 7) | (slot << 4)) ^ ((o & 7) << 4);
    srcRel[j] = o * DD + slot * 8;
  }

  // mat(i) = grp ? 4+i : (i<4 ? i : 8)
#define MATOF(i) (grp ? (4 + (i)) : (((i) < 4) ? (i) : 8))

  // prologue: stage mat(0) half0
  uint4 wreg[4];
  {
    const unsigned short* wsrc = WTl + (size_t)MATOF(0) * DD * DD;
#pragma unroll
    for (int j = 0; j < 4; ++j)
      wreg[j] = *reinterpret_cast<const uint4*>(wsrc + srcRel[j]);
  }
#pragma unroll
  for (int j = 0; j < 4; ++j)
    *reinterpret_cast<uint4*>(ldsW[0] + dstB[j]) = wreg[j];
  __syncthreads();                   // ldsE + ldsW[0] ready

  // prologue gather: first relation of this group
  bf16x8 fA[4], fB[4];
  {
    const int r0 = grp ? 4 : 0;
    gather_frag_lds(h, eidx, ldsE, blockBeg,
                    ldsO[lnode * NR + r0], ldsO[lnode * NR + r0 + 1], g, fA);
  }

  f32x4 acc[8];
#pragma unroll
  for (int t = 0; t < 8; ++t) acc[t] = (f32x4){0.f, 0.f, 0.f, 0.f};

  // phase P (guarded by nph): MFMA mat(P>>1) half(P&1); stage P+1; gather next rel on even P.
#define PH(P, CUR, NXT)                                                               \
  if ((P) < nph) {                                                                    \
    __syncthreads();                                                                  \
    if ((P) + 1 < nph) {                                                              \
      const unsigned short* wsrc = WTl                                                \
          + (size_t)MATOF(((P) + 1) >> 1) * DD * DD + (((P) + 1) & 1) * 64;           \
      _Pragma("unroll")                                                               \
      for (int j = 0; j < 4; ++j)                                                     \
        wreg[j] = *reinterpret_cast<const uint4*>(wsrc + srcRel[j]);                  \
    }                                                                                 \
    int gb = 0, ge = 0;                                                               \
    const int rn = ((P) >> 1) + 1;                                                    \
    if (((P) & 1) == 0 && rn < 4) {                                                   \
      const int lo = lnode * NR + (grp ? 4 : 0) + rn;                                 \
      gb = ldsO[lo]; ge = ldsO[lo + 1];                                               \
    }                                                                                 \
    _Pragma("unroll")                                                                 \
    for (int kl = 0; kl < 2; ++kl) {                                                  \
      _Pragma("unroll")                                                               \
      for (int t = 0; t < 8; ++t) {                                                   \
        const int addr = (((t * 16 + c) << 7) + ((kl * 4 + g) << 4)) ^ ((c & 7) << 4); \
        bf16x8 a = *reinterpret_cast<const bf16x8*>(ldsW[(P) & 1] + addr);            \
        acc[t] = __builtin_amdgcn_mfma_f32_16x16x32_bf16(                             \
            a, CUR[((P) & 1) * 2 + kl], acc[t], 0, 0, 0);                             \
      }                                                                               \
    }                                                                                 \
    if (((P) & 1) == 0) {                                                             \
      if (rn < 4) {                                                                   \
        gather_frag_lds(h, eidx, ldsE, blockBeg, gb, ge, g, NXT);                     \
      } else if (rn == 4 && grp == 0) {                                               \
        _Pragma("unroll")                                                             \
        for (int ks = 0; ks < 4; ++ks)                                                \
          NXT[ks] = *reinterpret_cast<const bf16x8*>(                                 \
              h + (size_t)nld * DD + ks * 32 + g * 8);                                \
      }                                                                               \
    }                                                                                 \
    if ((P) + 1 < nph) {                                                              \
      _Pragma("unroll")                                                               \
      for (int j = 0; j < 4; ++j)                                                     \
        *reinterpret_cast<uint4*>(ldsW[((P) + 1) & 1] + dstB[j]) = wreg[j];           \
    }                                                                                 \
  }

  PH(0, fA, fB)  PH(1, fA, fB)
  PH(2, fB, fA)  PH(3, fB, fA)
  PH(4, fA, fB)  PH(5, fA, fB)
  PH(6, fB, fA)  PH(7, fB, fA)
  PH(8, fA, fB)  PH(9, fA, fB)
#undef PH
#undef MATOF

  if (n >= NN) return;
  float* pout = (grp ? pB : pA) + (size_t)n * DD;
#pragma unroll
  for (int t = 0; t < 8; ++t)
    *reinterpret_cast<f32x4*>(pout + t * 16 + g * 4) = acc[t];
}

// ---------------- combine: out = pA + pB + bias ----------------
template<int OUTF32>
__global__ __launch_bounds__(256) void combine_kernel(
    const float* __restrict__ pA, const float* __restrict__ pB,
    const float* __restrict__ bias, void* __restrict__ out)
{
  const int i = blockIdx.x * 256 + threadIdx.x;   // quads; NN*DD/4 total
  if (i >= NN * DD / 4) return;
  const float4 a = reinterpret_cast<const float4*>(pA)[i];
  const float4 b = reinterpret_cast<const float4*>(pB)[i];
  const int col = (i * 4) & (DD - 1);
  const float4 bv = *reinterpret_cast<const float4*>(bias + col);
  float4 o;
  o.x = a.x + b.x + bv.x; o.y = a.y + b.y + bv.y;
  o.z = a.z + b.z + bv.z; o.w = a.w + b.w + bv.w;
  if (OUTF32) {
    reinterpret_cast<float4*>(out)[i] = o;
  } else {
    uint2 q;
    q.x = pk2(o.x, o.y);
    q.y = pk2(o.z, o.w);
    reinterpret_cast<uint2*>(out)[i] = q;
  }
}

extern "C" void kernel_launch(void* const* d_in, const int* in_sizes, int n_in,
                              void* d_out, int out_size, void* d_ws, size_t ws_size,
                              hipStream_t stream) {
  const int*   node_ids = (const int*)d_in[0];
  const int*   src   = (const int*)d_in[1];
  const int*   dst   = (const int*)d_in[2];
  const int*   etype = (const int*)d_in[3];
  const float* emb   = (const float*)d_in[4];
  const float* W1    = (const float*)d_in[5];
  const float* Ws1   = (const float*)d_in[6];
  const float* b1    = (const float*)d_in[7];
  const float* W2    = (const float*)d_in[8];
  const float* Ws2   = (const float*)d_in[9];
  const float* b2    = (const float*)d_in[10];

  // ws layout (~86.5 MB):
  //   h0   bf16 [NN*DD]  12.8 MB | h1 bf16 [NN*DD] 12.8 MB | WT bf16 [18*DD*DD] 0.59 MB
  //   off8 i32 [NB+1] | deg8 i32 [NB] | eidx i32 [NE] | bsum/bbase i32 [NCHUNK8]
  //   pA f32 [NN*DD] 25.6 MB | pB f32 [NN*DD] 25.6 MB
  char* p = (char*)d_ws;
  unsigned short* h0 = (unsigned short*)p;  p += (size_t)NN * DD * 2;
  unsigned short* h1 = (unsigned short*)p;  p += (size_t)NN * DD * 2;
  unsigned short* WT = (unsigned short*)p;  p += (size_t)18 * DD * DD * 2;
  int* off8          = (int*)p;             p += (size_t)(NB + 1) * 4;
  int* deg8          = (int*)p;             p += (size_t)NB * 4;
  int* eidx          = (int*)p;             p += (size_t)NE * 4;
  int* bsum          = (int*)p;             p += (size_t)NCHUNK8 * 4;
  int* bbase         = (int*)p;             p += (size_t)NCHUNK8 * 4;
  float* pA          = (float*)p;           p += (size_t)NN * DD * 4;
  float* pB          = (float*)p;

  const int eb = (NE + 255) / 256;
  const int tb = (NN + 63) / 64;     // 782
  const int cb = (NN * DD / 4 + 255) / 256;  // 6250

  convw_kernel<<<dim3(64, 18), 256, 0, stream>>>(W1, Ws1, W2, Ws2, WT);
  convh_kernel<<<(NN * 16) / 256, 256, 0, stream>>>(emb, node_ids, h0);
  hipMemsetAsync(deg8, 0, (size_t)NB * 4, stream);
  hist_kernel<<<eb, 256, 0, stream>>>(dst, etype, deg8);
  bsum_kernel<<<NCHUNK8, 256, 0, stream>>>(deg8, bsum);
  bscan_kernel<<<1, 256, 0, stream>>>(bsum, bbase);
  expand_kernel<<<NCHUNK8, 256, 0, stream>>>(deg8, bbase, off8);
  fill_kernel<<<eb, 256, 0, stream>>>(src, dst, etype, deg8, eidx);

  // layer 1
  layer_split_kernel<<<dim3(tb, 2), 256, 0, stream>>>(h0, off8, eidx, WT, pA, pB);
  combine_kernel<0><<<cb, 256, 0, stream>>>(pA, pB, b1, h1);
  // layer 2
  layer_split_kernel<<<dim3(tb, 2), 256, 0, stream>>>(h1, off8, eidx, WT + (size_t)9 * DD * DD, pA, pB);
  combine_kernel<1><<<cb, 256, 0, stream>>>(pA, pB, b2, (float*)d_out);
}

// Round 22
// 238.335 us; speedup vs baseline: 3.1990x; 1.3513x over previous
//
#include <hip/hip_runtime.h>
#include <hip/hip_bf16.h>

#define NN 50000
#define NE 600000
#define DD 128
#define NR 8
#define NB (NN * NR)                   // 400000 (dst,rel) bins
#define NCHUNK8 ((NB + 255) / 256)     // 1563 scan blocks
#define PERT ((NCHUNK8 + 255) / 256)   // 7 items/thread in bscan
#define CAPE 1024                      // LDS edge-slice capacity per block

typedef __attribute__((ext_vector_type(8))) short bf16x8;
typedef __attribute__((ext_vector_type(4))) float f32x4;

__device__ __forceinline__ unsigned short f2bf(float f) {
  __hip_bfloat16 h = __float2bfloat16(f);
  return *reinterpret_cast<unsigned short*>(&h);
}
__device__ __forceinline__ unsigned pk2(float lo, float hi) {
  return (unsigned)f2bf(lo) | ((unsigned)f2bf(hi) << 16);
}
__device__ __forceinline__ float bflo(unsigned u) { return __uint_as_float(u << 16); }
__device__ __forceinline__ float bfhi(unsigned u) { return __uint_as_float(u & 0xffff0000u); }

// ---------------- weight transpose+convert (coalesced LDS tile version) ----------------
// grid (64, 18): block = one 16x16 tile of one matrix. WT[m][o][d] = bf16(W[m][d][o])
__global__ __launch_bounds__(256) void convw_kernel(
    const float* __restrict__ W1, const float* __restrict__ Ws1,
    const float* __restrict__ W2, const float* __restrict__ Ws2,
    unsigned short* __restrict__ WT)
{
  __shared__ float tile[16][17];
  const int m = blockIdx.y;
  const int t8 = blockIdx.x;               // 0..63 : tile (di, oi) = (t8>>3, t8&7)
  const int d0 = (t8 >> 3) * 16, o0 = (t8 & 7) * 16;
  const float* src;
  if (m < 8)       src = W1 + (size_t)m * DD * DD;
  else if (m == 8) src = Ws1;
  else if (m < 17) src = W2 + (size_t)(m - 9) * DD * DD;
  else             src = Ws2;
  const int tx = threadIdx.x & 15, ty = threadIdx.x >> 4;
  tile[ty][tx] = src[(size_t)(d0 + ty) * DD + o0 + tx];   // coalesced in tx
  __syncthreads();
  WT[(size_t)m * DD * DD + (o0 + ty) * DD + d0 + tx] = f2bf(tile[tx][ty]);  // coalesced in tx
}

// ---------------- h0 = bf16(emb[node_ids]) ----------------
__global__ __launch_bounds__(256) void convh_kernel(
    const float* __restrict__ emb, const int* __restrict__ ids,
    unsigned short* __restrict__ h)
{
  const int gid = blockIdx.x * 256 + threadIdx.x;   // NN*16 total
  if (gid >= NN * 16) return;
  const int row = gid >> 4;
  const int off = (gid & 15) * 8;
  const int srcRow = ids[row];
  const float* src = emb + (size_t)srcRow * DD + off;
  const float4 a = *reinterpret_cast<const float4*>(src);
  const float4 b = *reinterpret_cast<const float4*>(src + 4);
  uint4 u;
  u.x = pk2(a.x, a.y); u.y = pk2(a.z, a.w);
  u.z = pk2(b.x, b.y); u.w = pk2(b.z, b.w);
  *reinterpret_cast<uint4*>(h + (size_t)row * DD + off) = u;
}

// ---------------- CSR build over (dst,rel) bins ----------------
__global__ __launch_bounds__(256) void hist_kernel(
    const int* __restrict__ dst, const int* __restrict__ et,
    int* __restrict__ deg)
{
  const int e = blockIdx.x * 256 + threadIdx.x;
  if (e < NE) atomicAdd(&deg[dst[e] * NR + et[e]], 1);
}

__global__ __launch_bounds__(256) void bsum_kernel(
    const int* __restrict__ deg, int* __restrict__ bsum)
{
  __shared__ int tmp[256];
  const int t = threadIdx.x;
  const int i = blockIdx.x * 256 + t;
  tmp[t] = (i < NB) ? deg[i] : 0;
  __syncthreads();
#pragma unroll
  for (int off = 128; off > 0; off >>= 1) {
    if (t < off) tmp[t] += tmp[t + off];
    __syncthreads();
  }
  if (t == 0) bsum[blockIdx.x] = tmp[0];
}

// 1 block: exclusive scan of bsum[NCHUNK8] -> bbase[NCHUNK8]; 7 items/thread
__global__ __launch_bounds__(256) void bscan_kernel(
    const int* __restrict__ bsum, int* __restrict__ bbase)
{
  __shared__ int tmp[256];
  const int t = threadIdx.x;
  const int b = t * PERT;
  const int e = min(b + PERT, NCHUNK8);
  int s = 0;
  for (int i = b; i < e; ++i) s += bsum[i];
  tmp[t] = s;
  __syncthreads();
#pragma unroll
  for (int off = 1; off < 256; off <<= 1) {
    const int x = (t >= off) ? tmp[t - off] : 0;
    __syncthreads();
    tmp[t] += x;
    __syncthreads();
  }
  int run = tmp[t] - s;        // exclusive base of this thread's chunk
  for (int i = b; i < e; ++i) {
    const int v = bsum[i];
    bbase[i] = run;
    run += v;
  }
}

__global__ __launch_bounds__(256) void expand_kernel(
    int* deg, const int* __restrict__ bbase, int* __restrict__ offsets)
{
  __shared__ int tmp[256];
  const int t = threadIdx.x;
  const int i = blockIdx.x * 256 + t;
  const int v = (i < NB) ? deg[i] : 0;
  tmp[t] = v;
  __syncthreads();
#pragma unroll
  for (int off = 1; off < 256; off <<= 1) {
    const int x = (t >= off) ? tmp[t - off] : 0;
    __syncthreads();
    tmp[t] += x;
    __syncthreads();
  }
  const int base = bbase[blockIdx.x];
  const int excl = base + tmp[t] - v;
  if (i < NB) {
    offsets[i] = excl;
    deg[i] = excl;                  // fill cursor
    if (i == NB - 1) offsets[NB] = base + tmp[t];
  }
}

// eidx[pos] = src, bucketed by (dst,rel)
__global__ __launch_bounds__(256) void fill_kernel(
    const int* __restrict__ src, const int* __restrict__ dst,
    const int* __restrict__ et, int* __restrict__ cursor,
    int* __restrict__ eidx)
{
  const int e = blockIdx.x * 256 + threadIdx.x;
  if (e < NE) {
    const int pos = atomicAdd(&cursor[dst[e] * NR + et[e]], 1);
    eidx[pos] = src[e];
  }
}

// ---------------- gather: sum h[src] rows of one bin into a B-fragment ----------------
__device__ __forceinline__ void gather_frag_lds(
    const unsigned short* __restrict__ h,
    const int* __restrict__ eidx, const int* ldsE, int blockBeg,
    int beg, int end, int g, bf16x8* frag)
{
  float s[4][8];
#pragma unroll
  for (int ks = 0; ks < 4; ++ks)
#pragma unroll
    for (int j = 0; j < 8; ++j) s[ks][j] = 0.f;
  for (int i = beg; i < end; ++i) {
    const int li = i - blockBeg;
    const int idx = (li < CAPE) ? ldsE[li] : eidx[i];
    const unsigned short* hp = h + (size_t)idx * DD + g * 8;
#pragma unroll
    for (int ks = 0; ks < 4; ++ks) {
      const uint4 q = *reinterpret_cast<const uint4*>(hp + ks * 32);
      s[ks][0] += bflo(q.x); s[ks][1] += bfhi(q.x);
      s[ks][2] += bflo(q.y); s[ks][3] += bfhi(q.y);
      s[ks][4] += bflo(q.z); s[ks][5] += bfhi(q.z);
      s[ks][6] += bflo(q.w); s[ks][7] += bfhi(q.w);
    }
  }
#pragma unroll
  for (int ks = 0; ks < 4; ++ks) {
    uint4 u;
    u.x = pk2(s[ks][0], s[ks][1]);
    u.y = pk2(s[ks][2], s[ks][3]);
    u.z = pk2(s[ks][4], s[ks][5]);
    u.w = pk2(s[ks][6], s[ks][7]);
    frag[ks] = *reinterpret_cast<bf16x8*>(&u);
  }
}

// ---------------- fused RGCN layer: 64 nodes/block, K-half W staging (R13/R18) ----------------
// 256 thr = 4 waves x 16 nodes. 18 phases: (rel 0..8) x (k-half 0,1).
// Block's CSR slice (offsets + edge indices) staged in LDS (contiguous by construction).
template<int OUTF32>
__global__ __launch_bounds__(256, 4) void layer_kernel(
    const unsigned short* __restrict__ h,      // [NN][128] bf16 (read-only)
    const int* __restrict__ off8, const int* __restrict__ eidx,
    const unsigned short* __restrict__ WTl,    // this layer: [9][128][128] bf16 [o][d]
    const float* __restrict__ bias,
    void* __restrict__ out)                    // [NN][128] bf16 or f32
{
  __shared__ __align__(16) char ldsW[2][DD * 64 * 2];   // 2 x 16 KB, XOR-swizzled
  __shared__ int ldsO[64 * NR + 1];                     // block's offset slice (2 KB)
  __shared__ int ldsE[CAPE];                            // block's edge slice  (4 KB)

  const int tid = threadIdx.x;
  const int rowBase = blockIdx.x * 64;
  const int lane = tid & 63;
  const int w = tid >> 6;            // 0..3
  const int c = lane & 15;           // node selector
  const int g = lane >> 4;           // k group
  const int n = rowBase + w * 16 + c;
  const int nld = (n < NN) ? n : (NN - 1);
  const int lnode = nld - rowBase;

  // ---- stage CSR slice ----
  const int nNodes = (NN - rowBase < 64) ? (NN - rowBase) : 64;
  const int onum = nNodes * NR + 1;
  for (int i = tid; i < onum; i += 256) ldsO[i] = off8[rowBase * NR + i];
  __syncthreads();
  const int blockBeg = ldsO[0];
  const int blockCnt = ldsO[onum - 1] - blockBeg;
  const int stCnt = (blockCnt < CAPE) ? blockCnt : CAPE;
  for (int i = tid; i < stCnt; i += 256) ldsE[i] = eidx[blockBeg + i];

  // W staging geometry: 1024 chunks of 16B per half; thread owns 4.
  // LDS row = 128B (64 bf16); swizzle byte ^= (o&7)<<4.
  int dstB[4], srcRel[4];
#pragma unroll
  for (int j = 0; j < 4; ++j) {
    const int i = tid + j * 256;     // 0..1023
    const int o = i >> 3, slot = i & 7;
    dstB[j] = ((o << 7) | (slot << 4)) ^ ((o & 7) << 4);
    srcRel[j] = o * DD + slot * 8;
  }

  uint4 wreg[4];
#pragma unroll
  for (int j = 0; j < 4; ++j)
    wreg[j] = *reinterpret_cast<const uint4*>(WTl + srcRel[j]);
#pragma unroll
  for (int j = 0; j < 4; ++j)
    *reinterpret_cast<uint4*>(ldsW[0] + dstB[j]) = wreg[j];
  __syncthreads();                   // ldsE + ldsW[0] ready

  bf16x8 fA[4], fB[4];
  gather_frag_lds(h, eidx, ldsE, blockBeg, ldsO[lnode * NR], ldsO[lnode * NR + 1], g, fA);

  f32x4 acc[8];
#pragma unroll
  for (int t = 0; t < 8; ++t) acc[t] = (f32x4){0.f, 0.f, 0.f, 0.f};

  // phase P: r=P>>1, hf=P&1; reads buf[P&1]; stages phase P+1 into buf[(P+1)&1];
  // gathers relation r+1 on even phases.
#define PH(P, CUR, NXT)                                                               \
  {                                                                                   \
    __syncthreads();                                                                  \
    if ((P) < 17) {                                                                   \
      const unsigned short* wsrc = WTl                                                \
          + (size_t)(((P) + 1) >> 1) * DD * DD + (((P) + 1) & 1) * 64;                \
      _Pragma("unroll")                                                               \
      for (int j = 0; j < 4; ++j)                                                     \
        wreg[j] = *reinterpret_cast<const uint4*>(wsrc + srcRel[j]);                  \
    }                                                                                 \
    int gb = 0, ge = 0;                                                               \
    if (((P) & 1) == 0 && ((P) >> 1) + 1 < NR) {                                      \
      const int lo = lnode * NR + ((P) >> 1) + 1;                                     \
      gb = ldsO[lo]; ge = ldsO[lo + 1];                                               \
    }                                                                                 \
    _Pragma("unroll")                                                                 \
    for (int kl = 0; kl < 2; ++kl) {                                                  \
      _Pragma("unroll")                                                               \
      for (int t = 0; t < 8; ++t) {                                                   \
        const int addr = (((t * 16 + c) << 7) + ((kl * 4 + g) << 4)) ^ ((c & 7) << 4); \
        bf16x8 a = *reinterpret_cast<const bf16x8*>(ldsW[(P) & 1] + addr);            \
        acc[t] = __builtin_amdgcn_mfma_f32_16x16x32_bf16(                             \
            a, CUR[((P) & 1) * 2 + kl], acc[t], 0, 0, 0);                             \
      }                                                                               \
    }                                                                                 \
    if (((P) & 1) == 0) {                                                             \
      if (((P) >> 1) + 1 < NR) {                                                      \
        gather_frag_lds(h, eidx, ldsE, blockBeg, gb, ge, g, NXT);                     \
      } else if (((P) >> 1) + 1 == NR) {                                              \
        _Pragma("unroll")                                                             \
        for (int ks = 0; ks < 4; ++ks)                                                \
          NXT[ks] = *reinterpret_cast<const bf16x8*>(                                 \
              h + (size_t)nld * DD + ks * 32 + g * 8);                                \
      }                                                                               \
    }                                                                                 \
    if ((P) < 17) {                                                                   \
      _Pragma("unroll")                                                               \
      for (int j = 0; j < 4; ++j)                                                     \
        *reinterpret_cast<uint4*>(ldsW[((P) + 1) & 1] + dstB[j]) = wreg[j];           \
    }                                                                                 \
  }

  PH(0, fA, fB)  PH(1, fA, fB)
  PH(2, fB, fA)  PH(3, fB, fA)
  PH(4, fA, fB)  PH(5, fA, fB)
  PH(6, fB, fA)  PH(7, fB, fA)
  PH(8, fA, fB)  PH(9, fA, fB)
  PH(10, fB, fA) PH(11, fB, fA)
  PH(12, fA, fB) PH(13, fA, fB)
  PH(14, fB, fA) PH(15, fB, fA)
  PH(16, fA, fB) PH(17, fA, fB)
#undef PH

  if (n >= NN) return;
  if (OUTF32) {
    float* dst = (float*)out + (size_t)n * DD;
#pragma unroll
    for (int t = 0; t < 8; ++t) {
      const int o0 = t * 16 + g * 4;
      const float4 bv = *reinterpret_cast<const float4*>(bias + o0);
      float4 o;
      o.x = acc[t][0] + bv.x; o.y = acc[t][1] + bv.y;
      o.z = acc[t][2] + bv.z; o.w = acc[t][3] + bv.w;
      *reinterpret_cast<float4*>(dst + o0) = o;
    }
  } else {
    unsigned short* dst = (unsigned short*)out + (size_t)n * DD;
#pragma unroll
    for (int t = 0; t < 8; ++t) {
      const int o0 = t * 16 + g * 4;
      const float4 bv = *reinterpret_cast<const float4*>(bias + o0);
      uint2 q;
      q.x = pk2(acc[t][0] + bv.x, acc[t][1] + bv.y);
      q.y = pk2(acc[t][2] + bv.z, acc[t][3] + bv.w);
      *reinterpret_cast<uint2*>(dst + o0) = q;
    }
  }
}

extern "C" void kernel_launch(void* const* d_in, const int* in_sizes, int n_in,
                              void* d_out, int out_size, void* d_ws, size_t ws_size,
                              hipStream_t stream) {
  const int*   node_ids = (const int*)d_in[0];
  const int*   src   = (const int*)d_in[1];
  const int*   dst   = (const int*)d_in[2];
  const int*   etype = (const int*)d_in[3];
  const float* emb   = (const float*)d_in[4];
  const float* W1    = (const float*)d_in[5];
  const float* Ws1   = (const float*)d_in[6];
  const float* b1    = (const float*)d_in[7];
  const float* W2    = (const float*)d_in[8];
  const float* Ws2   = (const float*)d_in[9];
  const float* b2    = (const float*)d_in[10];

  // ws layout (~35 MB):
  //   h0     bf16 [NN*DD]       12.8 MB
  //   h1     bf16 [NN*DD]       12.8 MB
  //   WT     bf16 [18*DD*DD]     0.59 MB
  //   off8   i32  [NB+1]         1.6 MB
  //   deg8   i32  [NB]           1.6 MB
  //   eidx   i32  [NE]           2.4 MB
  //   bsum/bbase i32 [NCHUNK8]
  char* p = (char*)d_ws;
  unsigned short* h0 = (unsigned short*)p;  p += (size_t)NN * DD * 2;
  unsigned short* h1 = (unsigned short*)p;  p += (size_t)NN * DD * 2;
  unsigned short* WT = (unsigned short*)p;  p += (size_t)18 * DD * DD * 2;
  int* off8          = (int*)p;             p += (size_t)(NB + 1) * 4;
  int* deg8          = (int*)p;             p += (size_t)NB * 4;
  int* eidx          = (int*)p;             p += (size_t)NE * 4;
  int* bsum          = (int*)p;             p += (size_t)NCHUNK8 * 4;
  int* bbase         = (int*)p;

  const int eb = (NE + 255) / 256;
  const int tb = (NN + 63) / 64;     // 782

  convw_kernel<<<dim3(64, 18), 256, 0, stream>>>(W1, Ws1, W2, Ws2, WT);
  convh_kernel<<<(NN * 16) / 256, 256, 0, stream>>>(emb, node_ids, h0);
  hipMemsetAsync(deg8, 0, (size_t)NB * 4, stream);
  hist_kernel<<<eb, 256, 0, stream>>>(dst, etype, deg8);
  bsum_kernel<<<NCHUNK8, 256, 0, stream>>>(deg8, bsum);
  bscan_kernel<<<1, 256, 0, stream>>>(bsum, bbase);
  expand_kernel<<<NCHUNK8, 256, 0, stream>>>(deg8, bbase, off8);
  fill_kernel<<<eb, 256, 0, stream>>>(src, dst, etype, deg8, eidx);

  layer_kernel<0><<<tb, 256, 0, stream>>>(h0, off8, eidx, WT, b1, h1);
  layer_kernel<1><<<tb, 256, 0, stream>>>(h1, off8, eidx, WT + (size_t)9 * DD * DD, b2, (float*)d_out);
}